// Round 5
// baseline (521.596 us; speedup 1.0000x reference)
//
#include <hip/hip_runtime.h>

#define NCOMP   100000
#define D_CA    12
#define D_COURT 4
#define D_CATE  4
#define D_TOT   20
#define NCAUSE  200
#define NCOURT  50
#define NRES    10
#define CHUNK   16

// cold path: scalar walk of a (possibly partial) chunk with per-run flushes
__device__ __forceinline__ void slow_chunk(long base, int jmax, float dw,
                                           const int* __restrict__ cause_idx,
                                           const int* __restrict__ court_idx,
                                           const int* __restrict__ cate_idx,
                                           const int* __restrict__ seg_ids,
                                           const float* __restrict__ time_interval,
                                           const float* lds_ca, const float* lds_court,
                                           const float* lds_cate, const float* lds_w,
                                           float* __restrict__ out) {
    float acc[D_TOT];
#pragma unroll 1
    for (int d = 0; d < D_TOT; ++d) acc[d] = 0.0f;
    int cur = seg_ids[base];
#pragma unroll 1
    for (int j = 0; j < jmax; ++j) {
        const int sj = seg_ids[base + j];
        if (sj != cur) {
#pragma unroll 1
            for (int o = 0; o < D_TOT; ++o) {
                float s = 0.0f;
#pragma unroll 1
                for (int d = 0; d < D_TOT; ++d) s += acc[d] * lds_w[o * D_TOT + d];
                atomicAdd(&out[cur * D_TOT + o], s);
            }
#pragma unroll 1
            for (int d = 0; d < D_TOT; ++d) acc[d] = 0.0f;
            cur = sj;
        }
        const int ca = cause_idx[base + j];
        const int co = court_idx[base + j];
        const int ct = cate_idx[base + j];
        const float t = time_interval[base + j];
        const float dec = __fdividef(dw, __logf(2.718281828459045f + t));
#pragma unroll 1
        for (int d = 0; d < D_CA; ++d) acc[d] += dec * lds_ca[ca * D_CA + d];
#pragma unroll 1
        for (int d = 0; d < D_COURT; ++d) acc[D_CA + d] += dec * lds_court[co * D_COURT + d];
#pragma unroll 1
        for (int d = 0; d < D_CATE; ++d) acc[D_CA + D_COURT + d] += dec * lds_cate[ct * D_CATE + d];
    }
#pragma unroll 1
    for (int o = 0; o < D_TOT; ++o) {
        float s = 0.0f;
#pragma unroll 1
        for (int d = 0; d < D_TOT; ++d) s += acc[d] * lds_w[o * D_TOT + d];
        atomicAdd(&out[cur * D_TOT + o], s);
    }
}

__global__ __launch_bounds__(256, 4)
void event_sum_kernel(const int* __restrict__ cause_idx,
                      const int* __restrict__ court_idx,
                      const int* __restrict__ cate_idx,
                      const int* __restrict__ seg_ids,
                      const float* __restrict__ time_interval,
                      const float* __restrict__ ca_table,
                      const float* __restrict__ court_table,
                      const float* __restrict__ cate_table,
                      const float* __restrict__ proj_w,
                      const float* __restrict__ decay_w,
                      int n_events,
                      float* __restrict__ out) {
    __shared__ __align__(16) float lds_ca[NCAUSE * D_CA];
    __shared__ __align__(16) float lds_court[NCOURT * D_COURT];
    __shared__ __align__(16) float lds_cate[NRES * D_CATE];
    __shared__ __align__(16) float lds_w[D_TOT * D_TOT];

    for (int i = threadIdx.x; i < NCAUSE * D_CA; i += 256) lds_ca[i] = ca_table[i];
    for (int i = threadIdx.x; i < NCOURT * D_COURT; i += 256) lds_court[i] = court_table[i];
    for (int i = threadIdx.x; i < NRES * D_CATE; i += 256) lds_cate[i] = cate_table[i];
    for (int i = threadIdx.x; i < D_TOT * D_TOT; i += 256) lds_w[i] = proj_w[i];
    __syncthreads();

    const float dw = decay_w[0];
    const int tid = blockIdx.x * 256 + threadIdx.x;
    const long base = (long)tid * CHUNK;
    if (base >= n_events) return;

    if (base + CHUNK > n_events) {  // partial tail chunk (not hit for E=2^22)
        slow_chunk(base, (int)(n_events - base), dw, cause_idx, court_idx, cate_idx,
                   seg_ids, time_interval, lds_ca, lds_court, lds_cate, lds_w, out);
        return;
    }

    const int4* seg4 = (const int4*)(seg_ids + base);
    const int4 s0 = seg4[0], s1 = seg4[1], s2 = seg4[2], s3 = seg4[3];
    const int first = s0.x, last = s3.w;

    // interior-company detection (sorted => value not in {first,last} means
    // a company fully contained in this chunk). P ~ 1e-5: cold path.
    const bool slow =
        ((s0.y != first) & (s0.y != last)) | ((s0.z != first) & (s0.z != last)) |
        ((s0.w != first) & (s0.w != last)) | ((s1.x != first) & (s1.x != last)) |
        ((s1.y != first) & (s1.y != last)) | ((s1.z != first) & (s1.z != last)) |
        ((s1.w != first) & (s1.w != last)) | ((s2.x != first) & (s2.x != last)) |
        ((s2.y != first) & (s2.y != last)) | ((s2.z != first) & (s2.z != last)) |
        ((s2.w != first) & (s2.w != last)) | ((s3.x != first) & (s3.x != last)) |
        ((s3.y != first) & (s3.y != last)) | ((s3.z != first) & (s3.z != last));

    if (slow) {
        slow_chunk(base, CHUNK, dw, cause_idx, court_idx, cate_idx,
                   seg_ids, time_interval, lds_ca, lds_court, lds_cate, lds_w, out);
        return;
    }

    const int4* ca4 = (const int4*)(cause_idx + base);
    const int4* co4 = (const int4*)(court_idx + base);
    const int4* ct4 = (const int4*)(cate_idx + base);
    const float4* tm4 = (const float4*)(time_interval + base);

    float accH[D_TOT], accT[D_TOT];
#pragma unroll
    for (int d = 0; d < D_TOT; ++d) { accH[d] = 0.0f; accT[d] = 0.0f; }

#define PROC(CA, CO, CT, T, S)                                                \
    do {                                                                      \
        const float dec  = __fdividef(dw, __logf(2.718281828459045f + (T)));  \
        const float decT = ((S) != first) ? dec : 0.0f;                       \
        const float decH = dec - decT;                                        \
        const float4* car = (const float4*)(lds_ca + (CA) * D_CA);            \
        const float4 a0 = car[0], a1 = car[1], a2 = car[2];                   \
        const float4 b0 = *(const float4*)(lds_court + (CO) * D_COURT);       \
        const float4 c0 = *(const float4*)(lds_cate + (CT) * D_CATE);         \
        accH[0]  += decH * a0.x;  accT[0]  += decT * a0.x;                    \
        accH[1]  += decH * a0.y;  accT[1]  += decT * a0.y;                    \
        accH[2]  += decH * a0.z;  accT[2]  += decT * a0.z;                    \
        accH[3]  += decH * a0.w;  accT[3]  += decT * a0.w;                    \
        accH[4]  += decH * a1.x;  accT[4]  += decT * a1.x;                    \
        accH[5]  += decH * a1.y;  accT[5]  += decT * a1.y;                    \
        accH[6]  += decH * a1.z;  accT[6]  += decT * a1.z;                    \
        accH[7]  += decH * a1.w;  accT[7]  += decT * a1.w;                    \
        accH[8]  += decH * a2.x;  accT[8]  += decT * a2.x;                    \
        accH[9]  += decH * a2.y;  accT[9]  += decT * a2.y;                    \
        accH[10] += decH * a2.z;  accT[10] += decT * a2.z;                    \
        accH[11] += decH * a2.w;  accT[11] += decT * a2.w;                    \
        accH[12] += decH * b0.x;  accT[12] += decT * b0.x;                    \
        accH[13] += decH * b0.y;  accT[13] += decT * b0.y;                    \
        accH[14] += decH * b0.z;  accT[14] += decT * b0.z;                    \
        accH[15] += decH * b0.w;  accT[15] += decT * b0.w;                    \
        accH[16] += decH * c0.x;  accT[16] += decT * c0.x;                    \
        accH[17] += decH * c0.y;  accT[17] += decT * c0.y;                    \
        accH[18] += decH * c0.z;  accT[18] += decT * c0.z;                    \
        accH[19] += decH * c0.w;  accT[19] += decT * c0.w;                    \
    } while (0)

#define GROUP(J, SV)                                                          \
    do {                                                                      \
        const int4 ca = ca4[J]; const int4 co = co4[J];                       \
        const int4 ct = ct4[J]; const float4 tm = tm4[J];                     \
        PROC(ca.x, co.x, ct.x, tm.x, SV.x);                                   \
        PROC(ca.y, co.y, ct.y, tm.y, SV.y);                                   \
        PROC(ca.z, co.z, ct.z, tm.z, SV.z);                                   \
        PROC(ca.w, co.w, ct.w, tm.w, SV.w);                                   \
    } while (0)

    GROUP(0, s0);
    GROUP(1, s1);
    GROUP(2, s2);
    GROUP(3, s3);
#undef GROUP
#undef PROC

    // flush head run (always) and tail run (if chunk spans a boundary)
#pragma unroll
    for (int o = 0; o < D_TOT; ++o) {
        float s = 0.0f;
#pragma unroll
        for (int d = 0; d < D_TOT; ++d) s += accH[d] * lds_w[o * D_TOT + d];
        atomicAdd(&out[first * D_TOT + o], s);
    }
    if (last != first) {
#pragma unroll
        for (int o = 0; o < D_TOT; ++o) {
            float s = 0.0f;
#pragma unroll
            for (int d = 0; d < D_TOT; ++d) s += accT[d] * lds_w[o * D_TOT + d];
            atomicAdd(&out[last * D_TOT + o], s);
        }
    }
}

extern "C" void kernel_launch(void* const* d_in, const int* in_sizes, int n_in,
                              void* d_out, int out_size, void* d_ws, size_t ws_size,
                              hipStream_t stream) {
    const int* cause_idx = (const int*)d_in[0];
    const int* court_idx = (const int*)d_in[1];
    const int* cate_idx  = (const int*)d_in[2];
    const int* seg_ids   = (const int*)d_in[3];
    const float* time_interval = (const float*)d_in[4];
    const float* ca_table      = (const float*)d_in[5];
    const float* court_table   = (const float*)d_in[6];
    const float* cate_table    = (const float*)d_in[7];
    const float* proj_w        = (const float*)d_in[8];
    const float* decay_w       = (const float*)d_in[9];
    float* out = (float*)d_out;
    const int n_events = in_sizes[0];

    // atomics accumulate into out: zero it (harness poisons with 0xAA)
    hipMemsetAsync(out, 0, (size_t)out_size * sizeof(float), stream);

    const int threads_total = (n_events + CHUNK - 1) / CHUNK;  // 262144
    const int blocks = (threads_total + 255) / 256;            // 1024
    event_sum_kernel<<<blocks, 256, 0, stream>>>(
        cause_idx, court_idx, cate_idx, seg_ids, time_interval,
        ca_table, court_table, cate_table, proj_w, decay_w,
        n_events, out);
}

// Round 6
// 184.928 us; speedup vs baseline: 2.8205x; 2.8205x over previous
//
#include <hip/hip_runtime.h>

#define NCOMP   100000
#define D_CA    12
#define D_COURT 4
#define D_CATE  4
#define D_TOT   20
#define NCAUSE  200
#define NCOURT  50
#define NRES    10
#define CHUNK   16
#define TPB     256
#define BLK_EV  (TPB * CHUNK)   // 4096 events per block
#define MAXSLOT 160             // company slots per block (span ~98 expected)

// flush one run's raw 20-dim sum into the block's LDS slot (or, if the block's
// company span overflows MAXSLOT -- never for this data -- project + global atomic)
__device__ __forceinline__ void flush_run(const float (&acc)[D_TOT], int c, int c_first,
                                          float* __restrict__ lds_slot,
                                          const float* __restrict__ lds_w,
                                          float* __restrict__ out) {
    const int slot = c - c_first;
    if (slot < MAXSLOT) {
#pragma unroll
        for (int d = 0; d < D_TOT; ++d)
            atomicAdd(&lds_slot[slot * D_TOT + d], acc[d]);
    } else {
#pragma unroll 1
        for (int o = 0; o < D_TOT; ++o) {
            float s = 0.0f;
#pragma unroll 1
            for (int d = 0; d < D_TOT; ++d) s += acc[d] * lds_w[o * D_TOT + d];
            atomicAdd(&out[c * D_TOT + o], s);
        }
    }
}

// cold path: scalar walk of a (possibly partial) chunk with per-run LDS flushes
__device__ __noinline__ void slow_chunk(long base, int jmax, float dw,
                                        const int* __restrict__ cause_idx,
                                        const int* __restrict__ court_idx,
                                        const int* __restrict__ cate_idx,
                                        const int* __restrict__ seg_ids,
                                        const float* __restrict__ time_interval,
                                        const float* lds_ca, const float* lds_court,
                                        const float* lds_cate, const float* lds_w,
                                        float* lds_slot, int c_first,
                                        float* __restrict__ out) {
    float acc[D_TOT];
#pragma unroll
    for (int d = 0; d < D_TOT; ++d) acc[d] = 0.0f;
    int cur = seg_ids[base];
#pragma unroll 1
    for (int j = 0; j < jmax; ++j) {
        const int sj = seg_ids[base + j];
        if (sj != cur) {
            flush_run(acc, cur, c_first, lds_slot, lds_w, out);
#pragma unroll
            for (int d = 0; d < D_TOT; ++d) acc[d] = 0.0f;
            cur = sj;
        }
        const int ca = cause_idx[base + j];
        const int co = court_idx[base + j];
        const int ct = cate_idx[base + j];
        const float t = time_interval[base + j];
        const float dec = __fdividef(dw, __logf(2.718281828459045f + t));
#pragma unroll 1
        for (int d = 0; d < D_CA; ++d) acc[d] += dec * lds_ca[ca * D_CA + d];
#pragma unroll 1
        for (int d = 0; d < D_COURT; ++d) acc[D_CA + d] += dec * lds_court[co * D_COURT + d];
#pragma unroll 1
        for (int d = 0; d < D_CATE; ++d) acc[D_CA + D_COURT + d] += dec * lds_cate[ct * D_CATE + d];
    }
    flush_run(acc, cur, c_first, lds_slot, lds_w, out);
}

__global__ __launch_bounds__(TPB)
void block_seg_kernel(const int* __restrict__ cause_idx,
                      const int* __restrict__ court_idx,
                      const int* __restrict__ cate_idx,
                      const int* __restrict__ seg_ids,
                      const float* __restrict__ time_interval,
                      const float* __restrict__ ca_table,
                      const float* __restrict__ court_table,
                      const float* __restrict__ cate_table,
                      const float* __restrict__ proj_w,
                      const float* __restrict__ decay_w,
                      int n_events,
                      float* __restrict__ out) {
    __shared__ __align__(16) float lds_ca[NCAUSE * D_CA];        // 2400 f
    __shared__ __align__(16) float lds_court[NCOURT * D_COURT];  // 200 f
    __shared__ __align__(16) float lds_cate[NRES * D_CATE];      // 40 f
    __shared__ __align__(16) float lds_w[D_TOT * D_TOT];         // 400 f
    __shared__ __align__(16) float lds_slot[MAXSLOT * D_TOT];    // 3200 f
    __shared__ int sh_c0, sh_c1;

    for (int i = threadIdx.x; i < NCAUSE * D_CA; i += TPB) lds_ca[i] = ca_table[i];
    for (int i = threadIdx.x; i < NCOURT * D_COURT; i += TPB) lds_court[i] = court_table[i];
    for (int i = threadIdx.x; i < NRES * D_CATE; i += TPB) lds_cate[i] = cate_table[i];
    for (int i = threadIdx.x; i < D_TOT * D_TOT; i += TPB) lds_w[i] = proj_w[i];
    for (int i = threadIdx.x; i < MAXSLOT * D_TOT; i += TPB) lds_slot[i] = 0.0f;
    if (threadIdx.x == 0) {
        const long b0 = (long)blockIdx.x * BLK_EV;
        long b1 = b0 + BLK_EV;
        if (b1 > n_events) b1 = n_events;
        sh_c0 = seg_ids[b0];
        sh_c1 = seg_ids[b1 - 1];
    }
    __syncthreads();

    const float dw = decay_w[0];
    const int c_first = sh_c0;
    const long base = (long)blockIdx.x * BLK_EV + (long)threadIdx.x * CHUNK;

    if (base < n_events) {
        if (base + CHUNK > n_events) {
            slow_chunk(base, (int)(n_events - base), dw, cause_idx, court_idx, cate_idx,
                       seg_ids, time_interval, lds_ca, lds_court, lds_cate, lds_w,
                       lds_slot, c_first, out);
        } else {
            const int4* seg4 = (const int4*)(seg_ids + base);
            const int4 s0 = seg4[0], s1 = seg4[1], s2 = seg4[2], s3 = seg4[3];
            const int first = s0.x, last = s3.w;

            const bool slow =
                ((s0.y != first) & (s0.y != last)) | ((s0.z != first) & (s0.z != last)) |
                ((s0.w != first) & (s0.w != last)) | ((s1.x != first) & (s1.x != last)) |
                ((s1.y != first) & (s1.y != last)) | ((s1.z != first) & (s1.z != last)) |
                ((s1.w != first) & (s1.w != last)) | ((s2.x != first) & (s2.x != last)) |
                ((s2.y != first) & (s2.y != last)) | ((s2.z != first) & (s2.z != last)) |
                ((s2.w != first) & (s2.w != last)) | ((s3.x != first) & (s3.x != last)) |
                ((s3.y != first) & (s3.y != last)) | ((s3.z != first) & (s3.z != last));

            if (slow) {
                slow_chunk(base, CHUNK, dw, cause_idx, court_idx, cate_idx,
                           seg_ids, time_interval, lds_ca, lds_court, lds_cate, lds_w,
                           lds_slot, c_first, out);
            } else {
                const int4* ca4 = (const int4*)(cause_idx + base);
                const int4* co4 = (const int4*)(court_idx + base);
                const int4* ct4 = (const int4*)(cate_idx + base);
                const float4* tm4 = (const float4*)(time_interval + base);

                float accH[D_TOT], accT[D_TOT];
#pragma unroll
                for (int d = 0; d < D_TOT; ++d) { accH[d] = 0.0f; accT[d] = 0.0f; }

#define PROC(CA, CO, CT, T, S)                                                \
    do {                                                                      \
        const float dec  = __fdividef(dw, __logf(2.718281828459045f + (T)));  \
        const float decT = ((S) != first) ? dec : 0.0f;                       \
        const float decH = dec - decT;                                        \
        const float4* car = (const float4*)(lds_ca + (CA) * D_CA);            \
        const float4 a0 = car[0], a1 = car[1], a2 = car[2];                   \
        const float4 b0 = *(const float4*)(lds_court + (CO) * D_COURT);       \
        const float4 c0 = *(const float4*)(lds_cate + (CT) * D_CATE);         \
        accH[0]  += decH * a0.x;  accT[0]  += decT * a0.x;                    \
        accH[1]  += decH * a0.y;  accT[1]  += decT * a0.y;                    \
        accH[2]  += decH * a0.z;  accT[2]  += decT * a0.z;                    \
        accH[3]  += decH * a0.w;  accT[3]  += decT * a0.w;                    \
        accH[4]  += decH * a1.x;  accT[4]  += decT * a1.x;                    \
        accH[5]  += decH * a1.y;  accT[5]  += decT * a1.y;                    \
        accH[6]  += decH * a1.z;  accT[6]  += decT * a1.z;                    \
        accH[7]  += decH * a1.w;  accT[7]  += decT * a1.w;                    \
        accH[8]  += decH * a2.x;  accT[8]  += decT * a2.x;                    \
        accH[9]  += decH * a2.y;  accT[9]  += decT * a2.y;                    \
        accH[10] += decH * a2.z;  accT[10] += decT * a2.z;                    \
        accH[11] += decH * a2.w;  accT[11] += decT * a2.w;                    \
        accH[12] += decH * b0.x;  accT[12] += decT * b0.x;                    \
        accH[13] += decH * b0.y;  accT[13] += decT * b0.y;                    \
        accH[14] += decH * b0.z;  accT[14] += decT * b0.z;                    \
        accH[15] += decH * b0.w;  accT[15] += decT * b0.w;                    \
        accH[16] += decH * c0.x;  accT[16] += decT * c0.x;                    \
        accH[17] += decH * c0.y;  accT[17] += decT * c0.y;                    \
        accH[18] += decH * c0.z;  accT[18] += decT * c0.z;                    \
        accH[19] += decH * c0.w;  accT[19] += decT * c0.w;                    \
    } while (0)

#define GROUP(J, SV)                                                          \
    do {                                                                      \
        const int4 ca = ca4[J]; const int4 co = co4[J];                       \
        const int4 ct = ct4[J]; const float4 tm = tm4[J];                     \
        PROC(ca.x, co.x, ct.x, tm.x, SV.x);                                   \
        PROC(ca.y, co.y, ct.y, tm.y, SV.y);                                   \
        PROC(ca.z, co.z, ct.z, tm.z, SV.z);                                   \
        PROC(ca.w, co.w, ct.w, tm.w, SV.w);                                   \
    } while (0)

                GROUP(0, s0);
                GROUP(1, s1);
                GROUP(2, s2);
                GROUP(3, s3);
#undef GROUP
#undef PROC

                flush_run(accH, first, c_first, lds_slot, lds_w, out);
                if (last != first)
                    flush_run(accT, last, c_first, lds_slot, lds_w, out);
            }
        }
    }

    __syncthreads();

    // epilogue: project each company slot once; plain store for interior
    // companies (owned by this block alone), atomicAdd for the 2 boundary ones
    const int nslots = sh_c1 - c_first + 1;
    const int capped = nslots < MAXSLOT ? nslots : MAXSLOT;
    for (int i = threadIdx.x; i < capped * D_TOT; i += TPB) {
        const int slot = i / D_TOT;
        const int o = i - slot * D_TOT;
        float s = 0.0f;
#pragma unroll
        for (int d = 0; d < D_TOT; ++d) s += lds_slot[slot * D_TOT + d] * lds_w[o * D_TOT + d];
        const int c = c_first + slot;
        if (slot == 0 || slot == nslots - 1) atomicAdd(&out[c * D_TOT + o], s);
        else out[c * D_TOT + o] = s;
    }
}

extern "C" void kernel_launch(void* const* d_in, const int* in_sizes, int n_in,
                              void* d_out, int out_size, void* d_ws, size_t ws_size,
                              hipStream_t stream) {
    const int* cause_idx = (const int*)d_in[0];
    const int* court_idx = (const int*)d_in[1];
    const int* cate_idx  = (const int*)d_in[2];
    const int* seg_ids   = (const int*)d_in[3];
    const float* time_interval = (const float*)d_in[4];
    const float* ca_table      = (const float*)d_in[5];
    const float* court_table   = (const float*)d_in[6];
    const float* cate_table    = (const float*)d_in[7];
    const float* proj_w        = (const float*)d_in[8];
    const float* decay_w       = (const float*)d_in[9];
    float* out = (float*)d_out;
    const int n_events = in_sizes[0];

    // boundary-company atomics + empty-company gaps need zeroed output
    hipMemsetAsync(out, 0, (size_t)out_size * sizeof(float), stream);

    const int blocks = (n_events + BLK_EV - 1) / BLK_EV;  // 1024
    block_seg_kernel<<<blocks, TPB, 0, stream>>>(
        cause_idx, court_idx, cate_idx, seg_ids, time_interval,
        ca_table, court_table, cate_table, proj_w, decay_w,
        n_events, out);
}